// Round 2
// baseline (682.381 us; speedup 1.0000x reference)
//
#include <hip/hip_runtime.h>
#include <math.h>

// Problem constants (match reference)
#define BB 32
#define SS 2048
#define DD 1024
#define BETA_C 0.1f
#define RHO_C 1.0f

#define TPB 256
#define NBLK_PER_T 1024       // blocks per tensor; grid = 2048 (8 blocks/CU)
#define NBLK (2 * NBLK_PER_T)
#define CHUNK_V4 16384        // float4 per block = 256 KB contiguous per block
// ws layout: float partial[NBLK] (8 KB) at +0; unsigned counter at +8192.
// Every partial slot is unconditionally written each call -> no zeroing needed;
// only the 4-byte counter is memset per iteration.

__device__ __forceinline__ float dot4(float4 a, float4 b) {
    return a.x * b.x + a.y * b.y + a.z * b.z + a.w * b.w;
}

__device__ __forceinline__ float log_sigmoid(float x) {
    // stable: min(x,0) - log1p(exp(-|x|))
    return fminf(x, 0.f) - log1pf(expf(-fabsf(x)));
}

// Fused: streaming dot (identical load structure to round 1) + last-block-done
// finalize. Removes the separate finalize launch and the float-atomic lp
// accumulation (per-block partial slots instead).
__global__ __launch_bounds__(TPB) void fused_kernel(
    const float* __restrict__ e1, const float* __restrict__ e2,
    const float* __restrict__ w,
    const float* __restrict__ lp1ref, const float* __restrict__ lp2ref,
    const float* __restrict__ pref,
    float* __restrict__ partial, unsigned* __restrict__ counter,
    float* __restrict__ out)
{
    const int t     = blockIdx.x >> 10;           // 0: e1, 1: e2
    const int j     = blockIdx.x & (NBLK_PER_T - 1);
    const int tid   = threadIdx.x;
    const int lane  = tid & 63;
    const int wid   = tid >> 6;

    const float4 wv = ((const float4*)w)[tid];    // vec_idx mod 256 == tid always
    const float4* p = (const float4*)(t ? e2 : e1)
                    + (long long)j * CHUNK_V4 + tid;

    float a0 = 0.f, a1 = 0.f, a2 = 0.f, a3 = 0.f;
    float a4 = 0.f, a5 = 0.f, a6 = 0.f, a7 = 0.f;
    #pragma unroll
    for (int k = 0; k < 64; k += 8) {
        const float4 v0 = p[(k + 0) * TPB];
        const float4 v1 = p[(k + 1) * TPB];
        const float4 v2 = p[(k + 2) * TPB];
        const float4 v3 = p[(k + 3) * TPB];
        const float4 v4 = p[(k + 4) * TPB];
        const float4 v5 = p[(k + 5) * TPB];
        const float4 v6 = p[(k + 6) * TPB];
        const float4 v7 = p[(k + 7) * TPB];
        a0 += dot4(v0, wv);
        a1 += dot4(v1, wv);
        a2 += dot4(v2, wv);
        a3 += dot4(v3, wv);
        a4 += dot4(v4, wv);
        a5 += dot4(v5, wv);
        a6 += dot4(v6, wv);
        a7 += dot4(v7, wv);
    }
    float s = ((a0 + a4) + (a1 + a5)) + ((a2 + a6) + (a3 + a7));

    // wave (64-lane) reduction
    #pragma unroll
    for (int off = 32; off > 0; off >>= 1)
        s += __shfl_down(s, off, 64);

    __shared__ float red[TPB / 64];
    __shared__ int   isLast;
    if (lane == 0) red[wid] = s;
    __syncthreads();
    if (tid == 0) {
        float tot = 0.f;
        #pragma unroll
        for (int i = 0; i < TPB / 64; i++) tot += red[i];
        // device-scope publish (cross-XCD L2s are not coherent; G16)
        __hip_atomic_store(&partial[blockIdx.x], tot,
                           __ATOMIC_RELEASE, __HIP_MEMORY_SCOPE_AGENT);
        const unsigned old = __hip_atomic_fetch_add(counter, 1u,
                           __ATOMIC_ACQ_REL, __HIP_MEMORY_SCOPE_AGENT);
        isLast = (old == NBLK - 1);
    }
    __syncthreads();
    if (!isLast) return;

    // ---- finalize (last block only) ----
    // sum w^2: 256 threads, 4 elems each, block reduce
    float sw2 = 0.f;
    for (int i = tid; i < DD; i += TPB) { const float x = w[i]; sw2 += x * x; }
    #pragma unroll
    for (int off = 32; off > 0; off >>= 1) sw2 += __shfl_down(sw2, off, 64);
    __shared__ float swred[TPB / 64];
    if (lane == 0) swred[wid] = sw2;

    // lp[o], o in [0,64): slots base = (o>>5)*1024 + (o&31)*32, 32 slots each.
    // 4 threads per output, 8 acquire-loads each, combine via shfl.
    const int o    = tid >> 2;
    const int q    = tid & 3;
    const int base = ((o >> 5) << 10) + ((o & 31) << 5) + (q << 3);
    float ps = 0.f;
    #pragma unroll
    for (int r = 0; r < 8; r++)
        ps += __hip_atomic_load(&partial[base + r],
                                __ATOMIC_ACQUIRE, __HIP_MEMORY_SCOPE_AGENT);
    ps += __shfl_down(ps, 1, 64);
    ps += __shfl_down(ps, 2, 64);

    __shared__ float lpsh[2 * BB];
    if (q == 0) lpsh[o] = ps;
    __syncthreads();

    if (tid < 64) {
        float sw2t = 0.f;
        #pragma unroll
        for (int i = 0; i < TPB / 64; i++) sw2t += swred[i];

        float ind = 0.f, gns = 0.f;
        if (tid < BB) {
            const float z = BETA_C * ((lpsh[tid] - lp1ref[tid])
                                    - (lpsh[BB + tid] - lp2ref[tid]));
            const float pr = pref[tid];
            const float l1 = -log_sigmoid(z);
            const float l2 = -log_sigmoid(-z);
            ind = pr * l1 + (1.f - pr) * l2;
            const float sig = 1.f / (1.f + expf(-z));
            const float dv  = sig - pr;                 // d(ind)/dz
            gns = 2.f * BETA_C * BETA_C * (float)SS * sw2t * dv * dv;
        }
        #pragma unroll
        for (int off = 32; off > 0; off >>= 1) {
            ind += __shfl_down(ind, off, 64);
            gns += __shfl_down(gns, off, 64);
        }
        if (tid == 0)
            out[0] = ind / (float)BB + RHO_C * sqrtf(gns / (float)BB);
    }
}

extern "C" void kernel_launch(void* const* d_in, const int* in_sizes, int n_in,
                              void* d_out, int out_size, void* d_ws, size_t ws_size,
                              hipStream_t stream) {
    const float* e1     = (const float*)d_in[0];
    const float* e2     = (const float*)d_in[1];
    const float* w      = (const float*)d_in[2];
    const float* lp1ref = (const float*)d_in[3];
    const float* lp2ref = (const float*)d_in[4];
    const float* pref   = (const float*)d_in[5];
    float* out = (float*)d_out;
    float*    partial = (float*)d_ws;                       // 8 KB
    unsigned* counter = (unsigned*)((char*)d_ws + 8192);    // 4 B

    hipMemsetAsync(counter, 0, sizeof(unsigned), stream);
    fused_kernel<<<NBLK, TPB, 0, stream>>>(e1, e2, w, lp1ref, lp2ref, pref,
                                           partial, counter, out);
}

// Round 3
// 488.930 us; speedup vs baseline: 1.3957x; 1.3957x over previous
//
#include <hip/hip_runtime.h>
#include <math.h>

// Problem constants (match reference)
#define BB 32
#define SS 2048
#define DD 1024
#define BETA_C 0.1f
#define RHO_C 1.0f

#define TPB 256
#define NBLK_PER_T 1024       // blocks per tensor; grid = 2048 (8 blocks/CU)
#define CHUNK_V4 16384        // float4 per block = 256 KB contiguous per block
// 32 blocks per 8 MiB batch row; chunk base ≡ 0 (mod 256 vec4) so each
// thread's w index is exactly threadIdx.x for every load.

typedef float vf4 __attribute__((ext_vector_type(4)));

__device__ __forceinline__ float dot4(vf4 a, vf4 b) {
    return a.x * b.x + a.y * b.y + a.z * b.z + a.w * b.w;
}

// lp[t*BB + b] = sum over e_t[b,:,:] * w (broadcast over S).
// Round-1 structure (two kernels, relaxed atomicAdd — ordered agent atomics
// cost +168us in round 2). Single change vs round 1: embedding loads are
// NON-TEMPORAL. Rationale: L3 retains ~half the 512MB inputs across
// iterations (FETCH_SIZE=268MB), line-interleaved with misses -> every 1KB
// wave-load pays miss latency AND fragments the HBM stream into scattered
// 128B requests (3.26 TB/s effective). nt = no-allocate: steady-state L3
// holds nothing, reads become clean contiguous HBM streams.
__global__ __launch_bounds__(TPB) void dot_kernel(
    const float* __restrict__ e1, const float* __restrict__ e2,
    const float* __restrict__ w, float* __restrict__ lp)
{
    const int t     = blockIdx.x >> 10;           // 0: e1, 1: e2
    const int j     = blockIdx.x & (NBLK_PER_T - 1);
    const int tid   = threadIdx.x;
    const int lane  = tid & 63;
    const int wid   = tid >> 6;
    const int batch = j >> 5;                     // 32 blocks per batch row

    const vf4 wv = ((const vf4*)w)[tid];          // vec_idx mod 256 == tid always
    const vf4* p = (const vf4*)(t ? e2 : e1)
                 + (long long)j * CHUNK_V4 + tid;

    float a0 = 0.f, a1 = 0.f, a2 = 0.f, a3 = 0.f;
    float a4 = 0.f, a5 = 0.f, a6 = 0.f, a7 = 0.f;
    #pragma unroll
    for (int k = 0; k < 64; k += 8) {
        const vf4 v0 = __builtin_nontemporal_load(p + (k + 0) * TPB);
        const vf4 v1 = __builtin_nontemporal_load(p + (k + 1) * TPB);
        const vf4 v2 = __builtin_nontemporal_load(p + (k + 2) * TPB);
        const vf4 v3 = __builtin_nontemporal_load(p + (k + 3) * TPB);
        const vf4 v4 = __builtin_nontemporal_load(p + (k + 4) * TPB);
        const vf4 v5 = __builtin_nontemporal_load(p + (k + 5) * TPB);
        const vf4 v6 = __builtin_nontemporal_load(p + (k + 6) * TPB);
        const vf4 v7 = __builtin_nontemporal_load(p + (k + 7) * TPB);
        a0 += dot4(v0, wv);
        a1 += dot4(v1, wv);
        a2 += dot4(v2, wv);
        a3 += dot4(v3, wv);
        a4 += dot4(v4, wv);
        a5 += dot4(v5, wv);
        a6 += dot4(v6, wv);
        a7 += dot4(v7, wv);
    }
    float s = ((a0 + a4) + (a1 + a5)) + ((a2 + a6) + (a3 + a7));

    // wave (64-lane) reduction
    #pragma unroll
    for (int off = 32; off > 0; off >>= 1)
        s += __shfl_down(s, off, 64);

    __shared__ float red[TPB / 64];
    if (lane == 0) red[wid] = s;
    __syncthreads();
    if (threadIdx.x == 0) {
        float tot = 0.f;
        #pragma unroll
        for (int i = 0; i < TPB / 64; i++) tot += red[i];
        atomicAdd(&lp[t * BB + batch], tot);   // 32 atomics per address, relaxed
    }
}

__device__ __forceinline__ float log_sigmoid(float x) {
    // stable: min(x,0) - log1p(exp(-|x|))
    return fminf(x, 0.f) - log1pf(expf(-fabsf(x)));
}

// One wave: closed-form loss + grad-norm term.
// grad wrt embeddings is rank-1: g1[b,s,d] = beta*(sigma(z_b)-p_b)*w[d], g2 = -g1
// => grad_norm_sq[b] = 2*beta^2*(sigma(z_b)-p_b)^2 * S * sum(w^2)
__global__ void finalize_kernel(
    const float* __restrict__ lp, const float* __restrict__ w,
    const float* __restrict__ lp1ref, const float* __restrict__ lp2ref,
    const float* __restrict__ pref, float* __restrict__ out)
{
    const int lane = threadIdx.x;   // 64 threads
    float sw2 = 0.f;
    for (int i = lane; i < DD; i += 64) { const float x = w[i]; sw2 += x * x; }
    #pragma unroll
    for (int off = 32; off > 0; off >>= 1) sw2 += __shfl_down(sw2, off, 64);
    sw2 = __shfl(sw2, 0, 64);       // broadcast sum w^2

    float ind = 0.f, gns = 0.f;
    if (lane < BB) {
        const float z = BETA_C * ((lp[lane] - lp1ref[lane]) - (lp[BB + lane] - lp2ref[lane]));
        const float p = pref[lane];
        const float l1 = -log_sigmoid(z);
        const float l2 = -log_sigmoid(-z);
        ind = p * l1 + (1.f - p) * l2;
        const float sig = 1.f / (1.f + expf(-z));
        const float dv  = sig - p;                  // d(ind)/dz
        gns = 2.f * BETA_C * BETA_C * (float)SS * sw2 * dv * dv;
    }
    #pragma unroll
    for (int off = 32; off > 0; off >>= 1) {
        ind += __shfl_down(ind, off, 64);
        gns += __shfl_down(gns, off, 64);
    }
    if (lane == 0)
        out[0] = ind / (float)BB + RHO_C * sqrtf(gns / (float)BB);
}

extern "C" void kernel_launch(void* const* d_in, const int* in_sizes, int n_in,
                              void* d_out, int out_size, void* d_ws, size_t ws_size,
                              hipStream_t stream) {
    const float* e1     = (const float*)d_in[0];
    const float* e2     = (const float*)d_in[1];
    const float* w      = (const float*)d_in[2];
    const float* lp1ref = (const float*)d_in[3];
    const float* lp2ref = (const float*)d_in[4];
    const float* pref   = (const float*)d_in[5];
    float* out = (float*)d_out;
    float* lp  = (float*)d_ws;   // lp1[32] then lp2[32]

    hipMemsetAsync(lp, 0, 2 * BB * sizeof(float), stream);
    dot_kernel<<<2 * NBLK_PER_T, TPB, 0, stream>>>(e1, e2, w, lp);
    finalize_kernel<<<1, 64, 0, stream>>>(lp, w, lp1ref, lp2ref, pref, out);
}